// Round 1
// baseline (776.347 us; speedup 1.0000x reference)
//
#include <hip/hip_runtime.h>
#include <hip/hip_bf16.h>
#include <stdint.h>

#define NN 65536
#define NE 1048576
#define E2 (NE + NN)      // edges + self loops = 1,114,112 (exactly 8704*128)
#define HID 128
#define LP 136            // LDS row pitch in bf16 elements (+16B pad)

typedef __attribute__((ext_vector_type(8))) __bf16 bf16x8;
typedef __attribute__((ext_vector_type(4))) float f32x4;

__device__ __forceinline__ uint16_t f2bf(float f){
    union { float f; uint32_t i; } v; v.f = f;
    uint32_t r = v.i + 0x7FFFu + ((v.i >> 16) & 1u);   // RNE
    return (uint16_t)(r >> 16);
}
__device__ __forceinline__ float bf2f(uint16_t u){
    union { uint32_t i; float f; } v; v.i = ((uint32_t)u) << 16; return v.f;
}
__device__ __forceinline__ uint32_t pk2(float a, float b){
    return (uint32_t)f2bf(a) | ((uint32_t)f2bf(b) << 16);
}
__device__ __forceinline__ void unpk(uint32_t u, float& lo, float& hi){
    union { uint32_t i; float f; } a, b; a.i = u << 16; b.i = u & 0xFFFF0000u;
    lo = a.f; hi = b.f;
}
// monotone float->uint encoding for unsigned atomicMax
__device__ __forceinline__ uint32_t encf(float x){
    union { float f; uint32_t u; } v; v.f = x;
    return (v.u & 0x80000000u) ? ~v.u : (v.u | 0x80000000u);
}
__device__ __forceinline__ float decf(uint32_t u){
    union { uint32_t u; float f; } v;
    v.u = (u & 0x80000000u) ? (u ^ 0x80000000u) : ~u;
    return v.f;
}

// ---- tiny helpers: stage one 64-elem half-row into LDS ----
__device__ __forceinline__ void stage_copy(const uint16_t* g, uint16_t* l){
    const uint4* gs = (const uint4*)g; uint4* ls = (uint4*)l;
    #pragma unroll
    for (int j = 0; j < 8; j++) ls[j] = gs[j];
}
__device__ __forceinline__ void stage_cvt(const float* g, uint16_t* l){
    const float4* gs = (const float4*)g; uint4* ls = (uint4*)l;
    #pragma unroll
    for (int j = 0; j < 8; j++){
        float4 f0 = gs[2*j], f1 = gs[2*j+1];
        uint4 o; o.x = pk2(f0.x, f0.y); o.y = pk2(f0.z, f0.w);
        o.z = pk2(f1.x, f1.y); o.w = pk2(f1.z, f1.w);
        ls[j] = o;
    }
}

// 128x128x128 bf16 GEMM tile: 4 waves, wave w does rows [32w,32w+32), acc[2][8]
// A layout: m=lane&15, k=quad*8+j ; B (from W^T[n][k]): n=lane&15, k=quad*8+j
__device__ __forceinline__ void gemm_tile(const uint16_t* Ts, const uint16_t* Ws,
                                          f32x4 (&acc)[2][8], int wv, int lq, int quad){
    #pragma unroll
    for (int k0 = 0; k0 < 128; k0 += 32){
        bf16x8 af[2], bfr[8];
        #pragma unroll
        for (int rt = 0; rt < 2; rt++)
            af[rt] = *(const bf16x8*)(Ts + (wv*32 + rt*16 + lq)*LP + k0 + quad*8);
        #pragma unroll
        for (int ct = 0; ct < 8; ct++)
            bfr[ct] = *(const bf16x8*)(Ws + (ct*16 + lq)*LP + k0 + quad*8);
        #pragma unroll
        for (int rt = 0; rt < 2; rt++)
            #pragma unroll
            for (int ct = 0; ct < 8; ct++)
                acc[rt][ct] = __builtin_amdgcn_mfma_f32_16x16x32_bf16(
                                  af[rt], bfr[ct], acc[rt][ct], 0, 0, 0);
    }
}

// ---------------- small prep kernels ----------------
__global__ void k_wT(const float* __restrict__ src, uint16_t* __restrict__ dst){
    int t = blockIdx.x * 256 + threadIdx.x;       // 16384 elems
    int n = t >> 7, k = t & 127;
    dst[n*128 + k] = f2bf(src[k*128 + n]);
}
__global__ void k_init_cnt(uint32_t* cnt){
    int i = blockIdx.x * 256 + threadIdx.x;
    if (i < NN) cnt[i] = 1u;                      // self-loop pre-counted
}
__global__ void k_hist(const int* __restrict__ ei, uint32_t* cnt){
    int e = blockIdx.x * 256 + threadIdx.x;
    if (e < NE) atomicAdd(&cnt[ei[NE + e]], 1u);
}
__global__ void k_scan(const uint32_t* __restrict__ cnt, uint32_t* __restrict__ cur){
    __shared__ uint32_t ps[1024];
    int t = threadIdx.x;
    int base = t * 64;
    uint32_t s = 0;
    for (int i = 0; i < 64; i++) s += cnt[base + i];
    ps[t] = s; __syncthreads();
    for (int off = 1; off < 1024; off <<= 1){
        uint32_t v = (t >= off) ? ps[t - off] : 0u;
        __syncthreads();
        ps[t] += v;
        __syncthreads();
    }
    uint32_t run = (t == 0) ? 0u : ps[t - 1];
    for (int i = 0; i < 64; i++){ cur[base + i] = run; run += cnt[base + i]; }
}
__global__ void k_scatter(const int* __restrict__ ei, uint32_t* cur,
                          uint32_t* __restrict__ ssrc, uint32_t* __restrict__ sdst){
    int e = blockIdx.x * 256 + threadIdx.x;
    if (e >= E2) return;
    uint32_t s, d;
    if (e < NE){ s = (uint32_t)ei[e]; d = (uint32_t)ei[NE + e]; }
    else { s = d = (uint32_t)(e - NE); }
    uint32_t p = atomicAdd(&cur[d], 1u);
    ssrc[p] = s; sdst[p] = d;
}
__global__ void k_init_agg(uint32_t* agg){
    int i = blockIdx.x * 256 + threadIdx.x;
    uint4 v = make_uint4(0x007FFFFFu, 0x007FFFFFu, 0x007FFFFFu, 0x007FFFFFu); // enc(-inf)
    ((uint4*)agg)[i] = v;
}

// ---------------- A/B precompute: B = pos@W1b ; A = x@W1a + B + b1 ----------------
__launch_bounds__(256, 2)
__global__ void k_ab(const float* __restrict__ xf, const uint16_t* __restrict__ xbf,
                     const float* __restrict__ pos,
                     const uint16_t* __restrict__ w1aT, const uint16_t* __restrict__ w1bT,
                     const float* __restrict__ lb1,
                     uint16_t* __restrict__ Abf, uint16_t* __restrict__ Bbf){
    __shared__ uint16_t Ts[128*LP];
    __shared__ uint16_t Ws[128*LP];
    __shared__ float b1s[128];
    const int tid = threadIdx.x;
    const int node0 = blockIdx.x * 128;
    if (tid < 128) b1s[tid] = lb1[tid];
    const int row = tid >> 1, half = tid & 1;
    uint16_t* lT = Ts + row*LP + half*64;
    uint16_t* lW = Ws + row*LP + half*64;

    // phase 1: pos tile (cvt) + W1b^T
    stage_cvt(pos + (size_t)(node0 + row)*HID + half*64, lT);
    stage_copy(w1bT + row*HID + half*64, lW);
    __syncthreads();

    const int wv = tid >> 6, lane = tid & 63, lq = lane & 15, quad = lane >> 4;
    f32x4 acc[2][8];
    #pragma unroll
    for (int a = 0; a < 2; a++)
        #pragma unroll
        for (int b = 0; b < 8; b++)
            acc[a][b] = (f32x4){0.f, 0.f, 0.f, 0.f};

    gemm_tile(Ts, Ws, acc, wv, lq, quad);
    __syncthreads();

    // save B = pos @ W1b  (C layout: col=lane&15, row=quad*4+reg)
    #pragma unroll
    for (int rt = 0; rt < 2; rt++)
        #pragma unroll
        for (int ct = 0; ct < 8; ct++)
            #pragma unroll
            for (int rg = 0; rg < 4; rg++){
                int r = node0 + wv*32 + rt*16 + quad*4 + rg;
                int c = ct*16 + lq;
                Bbf[(size_t)r*HID + c] = f2bf(acc[rt][ct][rg]);
            }

    // phase 2: x tile + W1a^T, continue accumulation
    if (xbf) stage_copy(xbf + (size_t)(node0 + row)*HID + half*64, lT);
    else     stage_cvt (xf  + (size_t)(node0 + row)*HID + half*64, lT);
    stage_copy(w1aT + row*HID + half*64, lW);
    __syncthreads();

    gemm_tile(Ts, Ws, acc, wv, lq, quad);

    #pragma unroll
    for (int rt = 0; rt < 2; rt++)
        #pragma unroll
        for (int ct = 0; ct < 8; ct++)
            #pragma unroll
            for (int rg = 0; rg < 4; rg++){
                int r = node0 + wv*32 + rt*16 + quad*4 + rg;
                int c = ct*16 + lq;
                Abf[(size_t)r*HID + c] = f2bf(acc[rt][ct][rg] + b1s[c]);
            }
}

// -------- edge kernel: h = relu(A[src]-B[dst]) @ W2 + b2 ; segmented max into agg --------
__launch_bounds__(256, 2)
__global__ void k_edge(const uint32_t* __restrict__ ssrc, const uint32_t* __restrict__ sdst,
                       const uint16_t* __restrict__ Abf, const uint16_t* __restrict__ Bbf,
                       const uint16_t* __restrict__ w2T, const float* __restrict__ lb2,
                       uint32_t* __restrict__ agg){
    __shared__ uint16_t Ts[128*LP];
    __shared__ uint16_t Ws[128*LP];
    __shared__ int ds_s[128];
    __shared__ float b2s[128];
    const int tid = threadIdx.x;
    const int e0 = blockIdx.x * 128;
    const int row = tid >> 1, half = tid & 1;

    if (tid < 128){ ds_s[tid] = (int)sdst[e0 + tid]; b2s[tid] = lb2[tid]; }
    stage_copy(w2T + row*HID + half*64, Ws + row*LP + half*64);

    // T staging with per-row gather (indices read directly; no extra sync needed)
    {
        int s = (int)ssrc[e0 + row];
        int d = (int)sdst[e0 + row];
        const uint4* ga = (const uint4*)(Abf + (size_t)s*HID + half*64);
        const uint4* gb = (const uint4*)(Bbf + (size_t)d*HID + half*64);
        uint4* lt4 = (uint4*)(Ts + row*LP + half*64);
        #pragma unroll
        for (int j = 0; j < 8; j++){
            uint4 ua = ga[j], ub = gb[j];
            float a0, a1, b0, b1;
            uint4 o;
            unpk(ua.x, a0, a1); unpk(ub.x, b0, b1);
            o.x = pk2(fmaxf(a0 - b0, 0.f), fmaxf(a1 - b1, 0.f));
            unpk(ua.y, a0, a1); unpk(ub.y, b0, b1);
            o.y = pk2(fmaxf(a0 - b0, 0.f), fmaxf(a1 - b1, 0.f));
            unpk(ua.z, a0, a1); unpk(ub.z, b0, b1);
            o.z = pk2(fmaxf(a0 - b0, 0.f), fmaxf(a1 - b1, 0.f));
            unpk(ua.w, a0, a1); unpk(ub.w, b0, b1);
            o.w = pk2(fmaxf(a0 - b0, 0.f), fmaxf(a1 - b1, 0.f));
            lt4[j] = o;
        }
    }
    __syncthreads();

    const int wv = tid >> 6, lane = tid & 63, lq = lane & 15, quad = lane >> 4;
    f32x4 acc[2][8];
    #pragma unroll
    for (int a = 0; a < 2; a++)
        #pragma unroll
        for (int b = 0; b < 8; b++)
            acc[a][b] = (f32x4){0.f, 0.f, 0.f, 0.f};

    gemm_tile(Ts, Ws, acc, wv, lq, quad);
    __syncthreads();                 // all Ts reads done -> reuse as C buffer

    uint16_t* Cs = Ts;
    #pragma unroll
    for (int rt = 0; rt < 2; rt++)
        #pragma unroll
        for (int ct = 0; ct < 8; ct++)
            #pragma unroll
            for (int rg = 0; rg < 4; rg++){
                int rr = wv*32 + rt*16 + quad*4 + rg;
                int c  = ct*16 + lq;
                Cs[rr*LP + c] = f2bf(acc[rt][ct][rg] + b2s[c]);
            }
    __syncthreads();

    // segmented run-max over sorted dst (branches are wave-uniform: same d per row)
    const int f = tid & 127, seg = tid >> 7;
    const int r0 = seg * 64;
    int pd = ds_s[r0];
    float cur = -__builtin_inff();
    for (int r = r0; r < r0 + 64; r++){
        int d = ds_s[r];
        if (d != pd){
            atomicMax(&agg[(size_t)pd*HID + f], encf(cur));
            cur = -__builtin_inff();
            pd = d;
        }
        cur = fmaxf(cur, bf2f(Cs[r*LP + f]));
    }
    atomicMax(&agg[(size_t)pd*HID + f], encf(cur));
}

// -------- global nn: out = relu(agg@G1 + c1) @ G2 + c2 --------
__launch_bounds__(256, 2)
__global__ void k_gnn(const uint32_t* __restrict__ agg,
                      const uint16_t* __restrict__ g1T, const uint16_t* __restrict__ g2T,
                      const float* __restrict__ gb1, const float* __restrict__ gb2,
                      float* __restrict__ outf, uint16_t* __restrict__ outb){
    __shared__ uint16_t Ts[128*LP];
    __shared__ uint16_t Ws[128*LP];
    __shared__ float c1s[128];
    __shared__ float c2s[128];
    const int tid = threadIdx.x;
    const int node0 = blockIdx.x * 128;
    if (tid < 128){ c1s[tid] = gb1[tid]; c2s[tid] = gb2[tid]; }
    const int row = tid >> 1, half = tid & 1;
    uint16_t* lW = Ws + row*LP + half*64;

    // stage decoded agg tile + G1^T
    {
        const uint4* ga = (const uint4*)(agg + (size_t)(node0 + row)*HID + half*64);
        uint16_t* lt = Ts + row*LP + half*64;
        #pragma unroll
        for (int j = 0; j < 16; j++){
            uint4 u = ga[j];
            uint2 o; o.x = pk2(decf(u.x), decf(u.y)); o.y = pk2(decf(u.z), decf(u.w));
            *(uint2*)(lt + j*4) = o;
        }
        stage_copy(g1T + row*HID + half*64, lW);
    }
    __syncthreads();

    const int wv = tid >> 6, lane = tid & 63, lq = lane & 15, quad = lane >> 4;
    f32x4 acc[2][8];
    #pragma unroll
    for (int a = 0; a < 2; a++)
        #pragma unroll
        for (int b = 0; b < 8; b++)
            acc[a][b] = (f32x4){0.f, 0.f, 0.f, 0.f};

    gemm_tile(Ts, Ws, acc, wv, lq, quad);
    __syncthreads();

    // P = relu(acc + c1) -> Ts ; restage Ws <- G2^T
    #pragma unroll
    for (int rt = 0; rt < 2; rt++)
        #pragma unroll
        for (int ct = 0; ct < 8; ct++)
            #pragma unroll
            for (int rg = 0; rg < 4; rg++){
                int rr = wv*32 + rt*16 + quad*4 + rg;
                int c  = ct*16 + lq;
                Ts[rr*LP + c] = f2bf(fmaxf(acc[rt][ct][rg] + c1s[c], 0.f));
            }
    stage_copy(g2T + row*HID + half*64, lW);
    __syncthreads();

    #pragma unroll
    for (int a = 0; a < 2; a++)
        #pragma unroll
        for (int b = 0; b < 8; b++)
            acc[a][b] = (f32x4){0.f, 0.f, 0.f, 0.f};

    gemm_tile(Ts, Ws, acc, wv, lq, quad);

    #pragma unroll
    for (int rt = 0; rt < 2; rt++)
        #pragma unroll
        for (int ct = 0; ct < 8; ct++)
            #pragma unroll
            for (int rg = 0; rg < 4; rg++){
                int r = node0 + wv*32 + rt*16 + quad*4 + rg;
                int c = ct*16 + lq;
                float v = acc[rt][ct][rg] + c2s[c];
                if (outf) outf[(size_t)r*HID + c] = v;
                else      outb[(size_t)r*HID + c] = f2bf(v);
            }
}

extern "C" void kernel_launch(void* const* d_in, const int* in_sizes, int n_in,
                              void* d_out, int out_size, void* d_ws, size_t ws_size,
                              hipStream_t stream){
    const float* x   = (const float*)d_in[0];
    const float* pos = (const float*)d_in[1];
    const int*   ei  = (const int*)d_in[2];
    const float* W[16];
    for (int i = 0; i < 16; i++) W[i] = (const float*)d_in[3 + i];
    // per layer l: lw1=W[8l+0] lb1=+1 lw2=+2 lb2=+3 gw1=+4 gb1=+5 gw2=+6 gb2=+7

    uint8_t* p = (uint8_t*)d_ws;
    uint16_t* wT[10];
    for (int i = 0; i < 10; i++) wT[i] = (uint16_t*)(p + (size_t)i * 32768);
    size_t off = 10 * 32768;
    uint16_t* h0   = (uint16_t*)(p + off); off += (size_t)NN * HID * 2;
    uint16_t* Abf  = (uint16_t*)(p + off); off += (size_t)NN * HID * 2;
    uint16_t* Bbf  = (uint16_t*)(p + off); off += (size_t)NN * HID * 2;
    uint32_t* agg  = (uint32_t*)(p + off); off += (size_t)NN * HID * 4;
    uint32_t* cnt  = (uint32_t*)(p + off); off += (size_t)NN * 4;
    uint32_t* cur  = (uint32_t*)(p + off); off += (size_t)NN * 4;
    uint32_t* ssrc = (uint32_t*)(p + off); off += (size_t)E2 * 4;
    uint32_t* sdst = (uint32_t*)(p + off); off += (size_t)E2 * 4;
    (void)ws_size; (void)in_sizes; (void)n_in; (void)out_size;

    // weight transpose+cvt: slots per layer: W1a^T, W1b^T, W2^T, G1^T, G2^T
    for (int l = 0; l < 2; l++){
        const float* lw1 = W[8*l + 0];
        k_wT<<<64, 256, 0, stream>>>(lw1,             wT[5*l + 0]);
        k_wT<<<64, 256, 0, stream>>>(lw1 + 128*128,   wT[5*l + 1]);
        k_wT<<<64, 256, 0, stream>>>(W[8*l + 2],      wT[5*l + 2]);
        k_wT<<<64, 256, 0, stream>>>(W[8*l + 4],      wT[5*l + 3]);
        k_wT<<<64, 256, 0, stream>>>(W[8*l + 6],      wT[5*l + 4]);
    }
    // dst-sorted edge list (shared by both layers)
    k_init_cnt<<<NN/256, 256, 0, stream>>>(cnt);
    k_hist<<<NE/256, 256, 0, stream>>>(ei, cnt);
    k_scan<<<1, 1024, 0, stream>>>(cnt, cur);
    k_scatter<<<E2/256, 256, 0, stream>>>(ei, cur, ssrc, sdst);

    for (int l = 0; l < 2; l++){
        const float* lb1 = W[8*l + 1], *lb2 = W[8*l + 3];
        const float* gb1 = W[8*l + 5], *gb2 = W[8*l + 7];
        k_ab<<<NN/128, 256, 0, stream>>>(l == 0 ? x : nullptr, l == 0 ? nullptr : h0,
                                         pos, wT[5*l + 0], wT[5*l + 1], lb1, Abf, Bbf);
        k_init_agg<<<(NN*HID/4)/256, 256, 0, stream>>>(agg);
        k_edge<<<E2/128, 256, 0, stream>>>(ssrc, sdst, Abf, Bbf, wT[5*l + 2], lb2, agg);
        k_gnn<<<NN/128, 256, 0, stream>>>(agg, wT[5*l + 3], wT[5*l + 4], gb1, gb2,
                                          l == 0 ? nullptr : (float*)d_out,
                                          l == 0 ? h0 : nullptr);
    }
}